// Round 1
// baseline (251.046 us; speedup 1.0000x reference)
//
#include <hip/hip_runtime.h>

#define T       256
#define BSHIFT  12
#define BSIZE   4096            // nodes per bucket
#define MAXNB   32              // max buckets (N<=131072)
#define M       32              // accumulate slices per bucket
#define EPB     4096            // edges per count/scatter block
#define EPT     (EPB / T)       // 16 edges per thread
#define HSTRIDE 260             // u16 row stride: 260*2 bytes, %8==0 for b64 reads

// ---------- count: per-THREAD-column histogram (no LDS atomics) ----------
// cntT[b * ebp + g] = #edges of block g in bucket b   (transposed for scan)
__global__ void k_count(const int* __restrict__ col, int* __restrict__ cntT,
                        int E, int nb, int ebp) {
    __shared__ unsigned short hist[MAXNB][HSTRIDE];   // 16.6 KB
    int t = threadIdx.x, g = blockIdx.x, lane = t & 63, wid = t >> 6;
    for (int b = 0; b < nb; ++b) hist[b][t] = 0;
    __syncthreads();
    int base = g * EPB;
    bool full = (base + EPB <= E);
    if (full) {
#pragma unroll
        for (int k = 0; k < EPT / 4; ++k) {
            int4 c = *(const int4*)(col + base + (t + k * T) * 4);
            ++hist[c.x >> BSHIFT][t];
            ++hist[c.y >> BSHIFT][t];
            ++hist[c.z >> BSHIFT][t];
            ++hist[c.w >> BSHIFT][t];
        }
    } else {
        for (int k = 0; k < EPT; ++k) {
            int e = base + t + k * T;
            if (e < E) ++hist[col[e] >> BSHIFT][t];
        }
    }
    __syncthreads();
    // reduce 256 per-thread counts per bucket: one wave per bucket (round-robin)
    for (int b = wid; b < nb; b += 4) {
        const unsigned short* hp = &hist[b][lane * 4];
        int s = (int)hp[0] + hp[1] + hp[2] + hp[3];
#pragma unroll
        for (int d = 32; d >= 1; d >>= 1) s += __shfl_xor(s, d, 64);
        if (lane == 0) cntT[b * ebp + g] = s;
    }
}

// ---------- scan: one block per bucket, shfl-based (3 barriers/round) ----------
__global__ void k_scan(const int* __restrict__ cntT, int* __restrict__ ofsT,
                       int* __restrict__ tot, int eb, int ebp) {
    __shared__ int wsum[4];
    __shared__ int carry;
    int b = blockIdx.x, t = threadIdx.x, lane = t & 63, wid = t >> 6;
    if (t == 0) carry = 0;
    __syncthreads();
    int rounds = (eb + T - 1) / T;
    for (int jr = 0; jr < rounds; ++jr) {
        int idx = jr * T + t;
        int v = (idx < eb) ? cntT[b * ebp + idx] : 0;
        int inc = v;
#pragma unroll
        for (int d = 1; d < 64; d <<= 1) {
            int o = __shfl_up(inc, d, 64);
            if (lane >= d) inc += o;
        }
        if (lane == 63) wsum[wid] = inc;
        __syncthreads();
        int add = carry;
        for (int w = 0; w < wid; ++w) add += wsum[w];
        if (idx < eb) ofsT[b * ebp + idx] = inc - v + add;
        __syncthreads();
        if (t == 0) carry += wsum[0] + wsum[1] + wsum[2] + wsum[3];
        __syncthreads();
    }
    if (t == 0) tot[b] = carry;
}

// ---------- scatter: two-phase per-thread cursors (no LDS atomics) ----------
// record.x = (col & 4095) << 17 | row  (row < 2^17), record.y = bits(w)
__global__ void k_scatter(const int* __restrict__ row, const int* __restrict__ col,
                          const float* __restrict__ w,
                          const int* __restrict__ cntT, const int* __restrict__ ofsT,
                          const int* __restrict__ tot,
                          int2* __restrict__ rec, int E, int nb, int ebp) {
    __shared__ unsigned short cur[MAXNB][HSTRIDE];    // 16.6 KB: per-thread cursors
    __shared__ int  lofs[MAXNB + 1];
    __shared__ int  btot[MAXNB];
    __shared__ int  rbase[MAXNB];
    __shared__ int2 buf[EPB];                         // 32 KB
    int t = threadIdx.x, g = blockIdx.x, lane = t & 63, wid = t >> 6;
    for (int b = 0; b < nb; ++b) cur[b][t] = 0;
    __syncthreads();

    int base = g * EPB;
    bool full = (base + EPB <= E);
    int4 c0, c1, c2, c3;
    // ---- phase 1: count (col values kept in registers on the full path) ----
    if (full) {
        c0 = *(const int4*)(col + base + (t + 0 * T) * 4);
        c1 = *(const int4*)(col + base + (t + 1 * T) * 4);
        c2 = *(const int4*)(col + base + (t + 2 * T) * 4);
        c3 = *(const int4*)(col + base + (t + 3 * T) * 4);
        ++cur[c0.x >> BSHIFT][t]; ++cur[c0.y >> BSHIFT][t];
        ++cur[c0.z >> BSHIFT][t]; ++cur[c0.w >> BSHIFT][t];
        ++cur[c1.x >> BSHIFT][t]; ++cur[c1.y >> BSHIFT][t];
        ++cur[c1.z >> BSHIFT][t]; ++cur[c1.w >> BSHIFT][t];
        ++cur[c2.x >> BSHIFT][t]; ++cur[c2.y >> BSHIFT][t];
        ++cur[c2.z >> BSHIFT][t]; ++cur[c2.w >> BSHIFT][t];
        ++cur[c3.x >> BSHIFT][t]; ++cur[c3.y >> BSHIFT][t];
        ++cur[c3.z >> BSHIFT][t]; ++cur[c3.w >> BSHIFT][t];
    } else {
        for (int k = 0; k < EPT; ++k) {
            int e = base + t + k * T;
            if (e < E) ++cur[col[e] >> BSHIFT][t];
        }
    }
    __syncthreads();

    // ---- per-bucket exclusive scan of the 256 per-thread counts ----
    for (int b = wid; b < nb; b += 4) {
        unsigned short* hp = &cur[b][lane * 4];
        int a0 = hp[0], a1 = hp[1], a2 = hp[2], a3 = hp[3];
        int tsum = a0 + a1 + a2 + a3;
        int inc = tsum;
#pragma unroll
        for (int d = 1; d < 64; d <<= 1) {
            int o = __shfl_up(inc, d, 64);
            if (lane >= d) inc += o;
        }
        int excl = inc - tsum;
        hp[0] = (unsigned short)excl;
        hp[1] = (unsigned short)(excl + a0);
        hp[2] = (unsigned short)(excl + a0 + a1);
        hp[3] = (unsigned short)(excl + a0 + a1 + a2);
        if (lane == 63) btot[b] = inc;
    }
    __syncthreads();

    if (t < 64) {
        // bucket bases from padded tot (x4), plus tile-local bucket offsets
        int tv = (t < nb) ? ((tot[t] + 3) & ~3) : 0;
        int incA = tv;
#pragma unroll
        for (int d = 1; d < 32; d <<= 1) {
            int o = __shfl_up(incA, d, 64);
            if (t >= d) incA += o;
        }
        int h = (t < nb) ? btot[t] : 0;
        int incB = h;
#pragma unroll
        for (int d = 1; d < 32; d <<= 1) {
            int o = __shfl_up(incB, d, 64);
            if (t >= d) incB += o;
        }
        if (t == 0) lofs[0] = 0;
        if (t < nb) {
            lofs[t + 1] = incB;
            rbase[t] = (incA - tv) + ofsT[t * ebp + g];
        }
    }
    __syncthreads();

    // ---- phase 2: place (same traversal order as phase 1) ----
    auto place = [&](int c, int r, float wv) {
        int bb = c >> BSHIFT;
        int o = cur[bb][t];
        cur[bb][t] = (unsigned short)(o + 1);
        int pos = lofs[bb] + o;
        buf[pos] = make_int2(((c & (BSIZE - 1)) << 17) | r, __float_as_int(wv));
    };
    if (full) {
        {
            int idx = base + (t + 0 * T) * 4;
            int4 r = *(const int4*)(row + idx);
            float4 wv = *(const float4*)(w + idx);
            place(c0.x, r.x, wv.x); place(c0.y, r.y, wv.y);
            place(c0.z, r.z, wv.z); place(c0.w, r.w, wv.w);
        }
        {
            int idx = base + (t + 1 * T) * 4;
            int4 r = *(const int4*)(row + idx);
            float4 wv = *(const float4*)(w + idx);
            place(c1.x, r.x, wv.x); place(c1.y, r.y, wv.y);
            place(c1.z, r.z, wv.z); place(c1.w, r.w, wv.w);
        }
        {
            int idx = base + (t + 2 * T) * 4;
            int4 r = *(const int4*)(row + idx);
            float4 wv = *(const float4*)(w + idx);
            place(c2.x, r.x, wv.x); place(c2.y, r.y, wv.y);
            place(c2.z, r.z, wv.z); place(c2.w, r.w, wv.w);
        }
        {
            int idx = base + (t + 3 * T) * 4;
            int4 r = *(const int4*)(row + idx);
            float4 wv = *(const float4*)(w + idx);
            place(c3.x, r.x, wv.x); place(c3.y, r.y, wv.y);
            place(c3.z, r.z, wv.z); place(c3.w, r.w, wv.w);
        }
    } else {
        for (int k = 0; k < EPT; ++k) {
            int e = base + t + k * T;
            if (e < E) {
                int c = col[e];
                place(c, row[e], w[e]);
            }
        }
    }
    __syncthreads();

    // ---- coalesced copy-out; bucket recovered monotonically from lofs ----
    int total = lofs[nb];
    int b = 0;
    for (int j = t; j < total; j += T) {
        while (j >= lofs[b + 1]) ++b;
        rec[rbase[b] + (j - lofs[b])] = buf[j];
    }
}

// ---------- accumulate: LDS scatter-add of one bucket slice (R9 form) ----------
template <bool HAS_SRC>
__global__ void k_acc(const int2* __restrict__ rec, const int* __restrict__ tot,
                      const float* __restrict__ src, float* __restrict__ part, int nb) {
    __shared__ float acc[BSIZE];
    __shared__ int   bst[MAXNB];
    int t = threadIdx.x, g = blockIdx.x;
    int b = g / M, m = g % M;
    if (t < 64) {                               // bucket bases from padded tot
        int tv = (t < nb) ? ((tot[t] + 3) & ~3) : 0;
        int inc = tv;
#pragma unroll
        for (int d = 1; d < 32; d <<= 1) {
            int o = __shfl_up(inc, d, 64);
            if (t >= d) inc += o;
        }
        if (t < nb) bst[t] = inc - tv;
    }
    for (int j = t; j < BSIZE; j += T) acc[j] = 0.0f;
    __syncthreads();
    int s  = bst[b];
    int tb = tot[b];
    int chunk = ((tb + M - 1) / M + 7) & ~7;    // x8 records per slice
    int lo = s + m * chunk;
    int hi = min(s + tb, lo + chunk);
    const int4* rec4 = (const int4*)rec;
    int i = lo + t * 8;
    for (; i + 7 < hi; i += T * 8) {
        int4 q0 = rec4[(i >> 1) + 0];
        int4 q1 = rec4[(i >> 1) + 1];
        int4 q2 = rec4[(i >> 1) + 2];
        int4 q3 = rec4[(i >> 1) + 3];
        float v0 = __int_as_float(q0.y), v1 = __int_as_float(q0.w);
        float v2 = __int_as_float(q1.y), v3 = __int_as_float(q1.w);
        float v4 = __int_as_float(q2.y), v5 = __int_as_float(q2.w);
        float v6 = __int_as_float(q3.y), v7 = __int_as_float(q3.w);
        if (HAS_SRC) {
            v0 *= src[q0.x & 0x1FFFF]; v1 *= src[q0.z & 0x1FFFF];
            v2 *= src[q1.x & 0x1FFFF]; v3 *= src[q1.z & 0x1FFFF];
            v4 *= src[q2.x & 0x1FFFF]; v5 *= src[q2.z & 0x1FFFF];
            v6 *= src[q3.x & 0x1FFFF]; v7 *= src[q3.z & 0x1FFFF];
        }
        atomicAdd(&acc[((unsigned)q0.x) >> 17], v0);
        atomicAdd(&acc[((unsigned)q0.z) >> 17], v1);
        atomicAdd(&acc[((unsigned)q1.x) >> 17], v2);
        atomicAdd(&acc[((unsigned)q1.z) >> 17], v3);
        atomicAdd(&acc[((unsigned)q2.x) >> 17], v4);
        atomicAdd(&acc[((unsigned)q2.z) >> 17], v5);
        atomicAdd(&acc[((unsigned)q3.x) >> 17], v6);
        atomicAdd(&acc[((unsigned)q3.z) >> 17], v7);
    }
    for (; i < hi; ++i) {                       // tail owned by exactly one thread
        int2 r = rec[i];
        float v = __int_as_float(r.y);
        if (HAS_SRC) v *= src[r.x & 0x1FFFF];
        atomicAdd(&acc[((unsigned)r.x) >> 17], v);
    }
    __syncthreads();
    float* dst = part + (size_t)g * BSIZE;
    for (int j = t; j < BSIZE; j += T) dst[j] = acc[j];
}

// ---------- reduce + pointwise ----------
__device__ __forceinline__ float reduceM(const float* __restrict__ part, int n) {
    int b = n >> BSHIFT, o = n & (BSIZE - 1);
    const float* pp = part + (size_t)b * M * BSIZE + o;
    float s = 0.0f;
#pragma unroll
    for (int m = 0; m < M; ++m) s += pp[(size_t)m * BSIZE];
    return s;
}

__global__ void k_red_dinv(const float* __restrict__ part, const float* __restrict__ x,
                           float* __restrict__ dinv, float* __restrict__ p, int N) {
    int i = blockIdx.x * blockDim.x + threadIdx.x;
    if (i < N) {
        float d  = reduceM(part, i) + 1.0f;     // +1 = self-loop
        float di = rsqrtf(d);
        dinv[i] = di;
        p[i] = di * x[i];
    }
}

__global__ void k_red_mlp(const float* __restrict__ part, const float* __restrict__ dinv,
                          const float* __restrict__ p,
                          const float* __restrict__ W1, const float* __restrict__ b1,
                          const float* __restrict__ W2,
                          float* __restrict__ q, int N) {
    int i = blockIdx.x * blockDim.x + threadIdx.x;
    if (i < N) {
        float di = dinv[i];
        float s  = di * reduceM(part, i) + di * p[i];
        float acc = 0.0f;
#pragma unroll
        for (int k = 0; k < 16; ++k) {
            float h = fmaxf(s * W1[k] + b1[k], 0.0f);
            acc += h * W2[k];
        }
        q[i] = di * acc;
    }
}

__global__ void k_red_out(const float* __restrict__ part, const float* __restrict__ dinv,
                          const float* __restrict__ q, const float* __restrict__ b2,
                          float* __restrict__ out, int N) {
    int i = blockIdx.x * blockDim.x + threadIdx.x;
    if (i < N) {
        float di = dinv[i];
        out[i] = di * reduceM(part, i) + di * q[i] + b2[0];
    }
}

extern "C" void kernel_launch(void* const* d_in, const int* in_sizes, int n_in,
                              void* d_out, int out_size, void* d_ws, size_t ws_size,
                              hipStream_t stream) {
    const float* x  = (const float*)d_in[0];
    const int*   ei = (const int*)  d_in[1];
    const float* ew = (const float*)d_in[2];
    const float* W1 = (const float*)d_in[3];
    const float* b1 = (const float*)d_in[4];
    const float* W2 = (const float*)d_in[5];
    const float* b2 = (const float*)d_in[6];

    const int N = in_sizes[0];       // x is [N,1]
    const int E = in_sizes[2];       // edge_attr is [E]
    const int* row = ei;             // edge_index[0] = source
    const int* col = ei + E;         // edge_index[1] = target
    const int nb  = (N + BSIZE - 1) >> BSHIFT;   // 25
    const int eb  = (E + EPB - 1) / EPB;         // 1221
    const int ebp = (eb + 63) & ~63;             // padded row length

    // workspace layout (~54.8 MB), 256 B aligned
    char* wsp = (char*)d_ws;
    auto take = [&](size_t bytes) {
        char* r = wsp; wsp += (bytes + 255) & ~(size_t)255; return (void*)r;
    };
    int2*  rec  = (int2*) take((size_t)(E + 4 * MAXNB) * 8);   // 40.07 MB
    float* part = (float*)take((size_t)nb * M * BSIZE * 4);    // 13.11 MB
    float* dinv = (float*)take((size_t)N * 4);
    float* p    = (float*)take((size_t)N * 4);
    float* q    = (float*)take((size_t)N * 4);
    int*   cntT = (int*)  take((size_t)MAXNB * ebp * 4);       // 0.16 MB
    int*   ofsT = (int*)  take((size_t)MAXNB * ebp * 4);       // 0.16 MB
    int*   tot  = (int*)  take(MAXNB * 4);

    float* out = (float*)d_out;

    const int nbk = (N + T - 1) / T;
    const int ab  = nb * M;                      // 800

    k_count  <<<eb, T, 0, stream>>>(col, cntT, E, nb, ebp);
    k_scan   <<<nb, T, 0, stream>>>(cntT, ofsT, tot, eb, ebp);
    k_scatter<<<eb, T, 0, stream>>>(row, col, ew, cntT, ofsT, tot, rec, E, nb, ebp);

    // degree
    k_acc<false><<<ab, T, 0, stream>>>(rec, tot, nullptr, part, nb);
    k_red_dinv  <<<nbk, T, 0, stream>>>(part, x, dinv, p, N);

    // layer 1
    k_acc<true><<<ab, T, 0, stream>>>(rec, tot, p, part, nb);
    k_red_mlp  <<<nbk, T, 0, stream>>>(part, dinv, p, W1, b1, W2, q, N);

    // layer 2
    k_acc<true><<<ab, T, 0, stream>>>(rec, tot, q, part, nb);
    k_red_out  <<<nbk, T, 0, stream>>>(part, dinv, q, b2, out, N);
}